// Round 9
// baseline (93.550 us; speedup 1.0000x reference)
//
#include <hip/hip_runtime.h>
#include <math.h>

// GMM score, rescaled: out_j = (E_w[td] - x_j) / sigma2_j
// w_i = exp(-0.5 (td_i - x_j)^2 / sigma2_j), sigma2_j = (exp(2 t_j ln25)-1)/(2 ln25)
//
// Model (R1-R7): dur = ~41us harness ws-poison fill (fixed) + kernel + ~5us gap.
// Kernel floor: v_exp_f32 ~20cyc issue-serial (throughput-bound: R2 JPT
// invariance); 4 pk ops + 2 exp per 2-eval bundle = 48 cyc -> ~41us.
// R3 sw-exp2 REGRESSION (73). R4 fence-fusion REGRESSION (140).
// R5 fused+global: 49.6 (latency). R6 fused+LDS: 43.7. R7 barriers 16->4:
// 43.6 -- NO CHANGE => residual is not barriers.
// Cycle accounting: R2 = 24.0 cyc/bundle (ds_read shared across 2 j's);
// R6/R7 = 25.6 (dedicated reads). Residual = ds_read issue slots.
// R8: read-sharing attempt FAILED CORRECTNESS -- loop bound k<CH/128 was
// PARTS=16-scaled; with PARTS=32 each thread must cover (CH/4)/PARTS=32
// groups = 16 iters x 2 reads => k<CH/256. R8 read past the chunk (into the
// other ping-pong buffer + reduce bufs), double-counting. absmax 20.2.
// R9 (this round): same kernel, loop bound FIXED (k < CH/256; max idx
// 31+64*15+32=1023; coverage 32 parts x 32 groups = 1024 = full chunk).
// Prediction: kernel 41.5-42.5us, total ~90.5-91.5us. If kernel >=43us:
// declare roofline (fill 41 + floor 41 + gap ~5 accounts all).

typedef float v2f __attribute__((ext_vector_type(2)));

#define BLK    256
#define JB     16    // j's per block
#define JLANES 8     // j-lanes (each thread owns 2 j's: jl, jl+8)
#define PARTS  32    // N-part groups per block (BLK/JLANES)
#define CH     4096  // td elements per LDS chunk (16 KB); x2 ping-pong

#if __has_builtin(__builtin_amdgcn_exp2f)
#define EXP2(x) __builtin_amdgcn_exp2f(x)
#else
#define EXP2(x) exp2f(x)
#endif

__device__ __forceinline__ float sigma2_of(float tj) {
  const float TWO_LOG_S = 6.4377516497364011f;   // 2*ln(25)
  return (__expf(TWO_LOG_S * tj) - 1.0f) / TWO_LOG_S;
}

__device__ __forceinline__ float4 load_pad(const float* __restrict__ td,
                                           int gi, int N) {
  // pad -> d^2 = inf -> exp2(-inf) = 0 (weightless)
  if (gi + 3 < N) return *(const float4*)(td + gi);
  float4 v;
  v.x = (gi + 0 < N) ? td[gi + 0] : 1e30f;
  v.y = (gi + 1 < N) ? td[gi + 1] : 1e30f;
  v.z = (gi + 2 < N) ? td[gi + 2] : 1e30f;
  v.w = (gi + 3 < N) ? td[gi + 3] : 1e30f;
  return v;
}

__launch_bounds__(BLK, 4)
__global__ void gmm_fused(const float* __restrict__ x,
                          const float* __restrict__ t,
                          const float* __restrict__ td,
                          float* __restrict__ out,
                          int N, int B) {
  __shared__ float lds[2][CH];          // ping-pong chunk buffers (32 KB)
  __shared__ float nbuf[PARTS * JB];
  __shared__ float dbuf[PARTS * JB];

  const int tid  = threadIdx.x;
  const int jl   = tid & (JLANES - 1);  // j-lane (0..7)
  const int part = tid >> 3;            // N-part group (0..31)
  const int j0   = blockIdx.x * JB + jl;
  const int j1   = j0 + JLANES;

  const float HALF_LOG2E = 0.72134752044448170f;  // 0.5 * log2(e)
  float rA = 0.0f, yA = 0.0f, rB = 0.0f, yB = 0.0f;
  if (j0 < B) {
    float s2 = sigma2_of(t[j0]);
    rA = __fsqrt_rn(HALF_LOG2E / s2);   // d = (td - x)*r ; arg = -d^2 (base-2)
    yA = x[j0] * rA;
  }
  if (j1 < B) {
    float s2 = sigma2_of(t[j1]);
    rB = __fsqrt_rn(HALF_LOG2E / s2);
    yB = x[j1] * rB;
  }

  const v2f rvA  = {rA, rA};
  const v2f nyvA = {-yA, -yA};
  const v2f rvB  = {rB, rB};
  const v2f nyvB = {-yB, -yB};

  // accumulators: 2 num + 2 den (v2f) per j  -> 8 v2f = 16 VGPR
  v2f nA0 = {0.f, 0.f}, nA1 = {0.f, 0.f}, dA0 = {0.f, 0.f}, dA1 = {0.f, 0.f};
  v2f nB0 = {0.f, 0.f}, nB1 = {0.f, 0.f}, dB0 = {0.f, 0.f}, dB1 = {0.f, 0.f};

  // one LDS read feeds BOTH j's: 2 exp streams per v2f, 8 per f4-pair
#define GROUP2(v, nA, dA, nB, dB)                                       \
  {                                                                     \
    v2f ddA = __builtin_elementwise_fma(v, rvA, nyvA);                  \
    v2f ddB = __builtin_elementwise_fma(v, rvB, nyvB);                  \
    v2f qqA = ddA * ddA;                                                \
    v2f qqB = ddB * ddB;                                                \
    v2f ppA, ppB;                                                       \
    ppA.x = EXP2(-qqA.x); ppA.y = EXP2(-qqA.y);                         \
    ppB.x = EXP2(-qqB.x); ppB.y = EXP2(-qqB.y);                         \
    dA += ppA;                                                          \
    dB += ppB;                                                          \
    nA = __builtin_elementwise_fma(ppA, v, nA);                         \
    nB = __builtin_elementwise_fma(ppB, v, nB);                         \
  }

  const int NC = (N + CH - 1) / CH;     // 4 chunks for N=16384

  // stage chunk 0 into buffer 0 (4 coalesced float4 slots per thread)
  {
    float4 s0 = load_pad(td, (tid          ) * 4, N);
    float4 s1 = load_pad(td, (tid +     BLK) * 4, N);
    float4 s2 = load_pad(td, (tid + 2 * BLK) * 4, N);
    float4 s3 = load_pad(td, (tid + 3 * BLK) * 4, N);
    float4* dst = (float4*)lds[0];
    dst[tid]           = s0;
    dst[tid +     BLK] = s1;
    dst[tid + 2 * BLK] = s2;
    dst[tid + 3 * BLK] = s3;
  }
  __syncthreads();

  for (int c = 0; c < NC; ++c) {
    // T14 issue-early: next chunk's global loads before compute; vmcnt wait
    // lands at the ds_write after compute.
    float4 s0 = {0,0,0,0}, s1 = {0,0,0,0}, s2 = {0,0,0,0}, s3 = {0,0,0,0};
    const bool more = (c + 1 < NC);
    if (more) {
      const int nb = (c + 1) * CH;
      s0 = load_pad(td, nb + (tid          ) * 4, N);
      s1 = load_pad(td, nb + (tid +     BLK) * 4, N);
      s2 = load_pad(td, nb + (tid + 2 * BLK) * 4, N);
      s3 = load_pad(td, nb + (tid + 3 * BLK) * 4, N);
    }

    // compute current chunk from buf[c&1]; this thread's share:
    // f4 groups g = part + 64k and g+32, k = 0..CH/256-1 (16 iters x 2 reads
    // = 32 groups/thread; 32 parts x 32 = 1024 groups = full chunk; max idx
    // 31+64*15+32 = 1023). 8 distinct b128 addrs/wave: conflict-free.
    const float4* l4 = (const float4*)lds[c & 1];
    #pragma unroll 4
    for (int k = 0; k < CH / 256; ++k) {
      float4 v0 = l4[part + 2 * PARTS * k];
      float4 v1 = l4[part + 2 * PARTS * k + PARTS];
      v2f va = {v0.x, v0.y}, vb = {v0.z, v0.w};
      v2f vc = {v1.x, v1.y}, vd = {v1.z, v1.w};
      GROUP2(va, nA0, dA0, nB0, dB0)
      GROUP2(vb, nA1, dA1, nB1, dB1)
      GROUP2(vc, nA0, dA0, nB0, dB0)
      GROUP2(vd, nA1, dA1, nB1, dB1)
    }

    if (more) {
      // write next chunk into the idle buffer; prev iteration's barrier
      // guarantees every wave is done reading it. ONE barrier per chunk.
      float4* dst = (float4*)lds[(c + 1) & 1];
      dst[tid]           = s0;
      dst[tid +     BLK] = s1;
      dst[tid + 2 * BLK] = s2;
      dst[tid + 3 * BLK] = s3;
      __syncthreads();
    }
  }
#undef GROUP2

  v2f numvA = nA0 + nA1, denvA = dA0 + dA1;
  v2f numvB = nB0 + nB1, denvB = dB0 + dB1;
  __syncthreads();   // all waves past last compute before reduce buffers fill
  nbuf[part * JB + jl]          = numvA.x + numvA.y;
  dbuf[part * JB + jl]          = denvA.x + denvA.y;
  nbuf[part * JB + jl + JLANES] = numvB.x + numvB.y;
  dbuf[part * JB + jl + JLANES] = denvB.x + denvB.y;
  __syncthreads();

  // Final combine: 16 threads, each sums 32 part-partials for its j.
  if (tid < JB && (blockIdx.x * JB + tid) < B) {
    const int jj = blockIdx.x * JB + tid;
    float num = 0.f, den = 0.f;
    #pragma unroll
    for (int p = 0; p < PARTS; ++p) {
      num += nbuf[p * JB + tid];   // lanes read consecutive floats: clean
      den += dbuf[p * JB + tid];
    }
    float sigma2 = sigma2_of(t[jj]);
    float evals = (den == 0.0f) ? 0.0f : (num / den);   // reference's guard
    out[jj] = (evals - x[jj]) / sigma2;
  }
}

extern "C" void kernel_launch(void* const* d_in, const int* in_sizes, int n_in,
                              void* d_out, int out_size, void* d_ws, size_t ws_size,
                              hipStream_t stream) {
  const float* x  = (const float*)d_in[0];
  const float* t  = (const float*)d_in[1];
  const float* td = (const float*)d_in[2];
  float* out = (float*)d_out;
  (void)d_ws; (void)ws_size;

  const int B = in_sizes[0];
  const int N = in_sizes[2];

  const int GX = (B + JB - 1) / JB;   // 1024 blocks for B=16384
  gmm_fused<<<GX, BLK, 0, stream>>>(x, t, td, out, N, B);
}

// Round 10
// 91.437 us; speedup vs baseline: 1.0231x; 1.0231x over previous
//
#include <hip/hip_runtime.h>
#include <math.h>

// GMM score, rescaled: out_j = (E_w[td] - x_j) / sigma2_j
// w_i = exp(-0.5 (td_i - x_j)^2 / sigma2_j), sigma2_j = (exp(2 t_j ln25)-1)/(2 ln25)
//
// FINAL MODEL (R1-R9): dur = ~41us harness ws-poison fill (fixed; 256MiB at
// 83% HBM peak = its own roofline) + kernel + ~7us launch/gap.
// Kernel floor ~41us: 2.68e8 v_exp_f32 evals at ~20cyc/wave64-instr,
// issue-serial on the SIMD port (throughput-bound: R2 JPT-invariance), plus
// 4 pk-VALU ops per 2-eval bundle (48 cyc/bundle total).
// Falsified alternatives: R3 sw-exp2 poly (73us -- v_exp_f32 unbeatable in
// sw); R4 fence-fused reduction (140us -- per-block device-scope fence =
// cross-XCD L2 writeback x1024); R5 fused+global-load (49.6 -- latency);
// R7 barrier halving (no change); R9 ds_read sharing (44.1 + bank conflicts
// -- no change). Residual ~2.7us (3%) unattributed micro-overhead.
// This round: REVERT to R7 (best verified: kernel 43.6us, absmax 0.0039,
// 0 conflicts; total 92.4-92.5). Structure at roofline barring counter
// surprise.

typedef float v2f __attribute__((ext_vector_type(2)));

#define BLK   256
#define JB    16     // j's per block
#define PARTS 16     // N-part groups per block (BLK/JB)
#define CH    4096   // td elements per LDS chunk (16 KB); x2 ping-pong

#if __has_builtin(__builtin_amdgcn_exp2f)
#define EXP2(x) __builtin_amdgcn_exp2f(x)
#else
#define EXP2(x) exp2f(x)
#endif

__device__ __forceinline__ float sigma2_of(float tj) {
  const float TWO_LOG_S = 6.4377516497364011f;   // 2*ln(25)
  return (__expf(TWO_LOG_S * tj) - 1.0f) / TWO_LOG_S;
}

__device__ __forceinline__ float4 load_pad(const float* __restrict__ td,
                                           int gi, int N) {
  // pad -> d^2 = inf -> exp2(-inf) = 0 (weightless)
  if (gi + 3 < N) return *(const float4*)(td + gi);
  float4 v;
  v.x = (gi + 0 < N) ? td[gi + 0] : 1e30f;
  v.y = (gi + 1 < N) ? td[gi + 1] : 1e30f;
  v.z = (gi + 2 < N) ? td[gi + 2] : 1e30f;
  v.w = (gi + 3 < N) ? td[gi + 3] : 1e30f;
  return v;
}

__launch_bounds__(BLK, 4)
__global__ void gmm_fused(const float* __restrict__ x,
                          const float* __restrict__ t,
                          const float* __restrict__ td,
                          float* __restrict__ out,
                          int N, int B) {
  __shared__ float lds[2][CH];          // ping-pong chunk buffers (32 KB)
  __shared__ float nbuf[PARTS * JB];
  __shared__ float dbuf[PARTS * JB];

  const int tid  = threadIdx.x;
  const int jl   = tid & (JB - 1);      // j-lane within block
  const int part = tid >> 4;            // N-part group (0..15)
  const int j    = blockIdx.x * JB + jl;

  float r = 0.0f, y = 0.0f;
  if (j < B) {
    const float HALF_LOG2E = 0.72134752044448170f;  // 0.5 * log2(e)
    float s2 = sigma2_of(t[j]);
    r = __fsqrt_rn(HALF_LOG2E / s2);   // d = (td - x)*r ; arg = -d^2 (base-2)
    y = x[j] * r;
  }

  const v2f rv  = {r, r};
  const v2f nyv = {-y, -y};

  // accumulators persist across chunks: 4 num + 4 den (v2f)
  v2f n0 = {0.f, 0.f}, n1 = {0.f, 0.f}, n2 = {0.f, 0.f}, n3 = {0.f, 0.f};
  v2f d0 = {0.f, 0.f}, d1 = {0.f, 0.f}, d2 = {0.f, 0.f}, d3 = {0.f, 0.f};

#define GROUP(v, nacc, dacc)                                            \
  {                                                                     \
    v2f dd = __builtin_elementwise_fma(v, rv, nyv);                     \
    v2f qq = dd * dd;                                                   \
    v2f pp;                                                             \
    pp.x = EXP2(-qq.x); pp.y = EXP2(-qq.y);                             \
    dacc += pp;                                                         \
    nacc = __builtin_elementwise_fma(pp, v, nacc);                      \
  }

  const int NC = (N + CH - 1) / CH;     // 4 chunks for N=16384

  // stage chunk 0 into buffer 0 (4 coalesced float4 slots per thread)
  {
    float4 s0 = load_pad(td, (tid          ) * 4, N);
    float4 s1 = load_pad(td, (tid +     BLK) * 4, N);
    float4 s2 = load_pad(td, (tid + 2 * BLK) * 4, N);
    float4 s3 = load_pad(td, (tid + 3 * BLK) * 4, N);
    float4* dst = (float4*)lds[0];
    dst[tid]           = s0;
    dst[tid +     BLK] = s1;
    dst[tid + 2 * BLK] = s2;
    dst[tid + 3 * BLK] = s3;
  }
  __syncthreads();

  for (int c = 0; c < NC; ++c) {
    // T14 issue-early: next chunk's global loads go out before compute,
    // their vmcnt wait lands at the ds_write below (after compute).
    float4 s0 = {0,0,0,0}, s1 = {0,0,0,0}, s2 = {0,0,0,0}, s3 = {0,0,0,0};
    const bool more = (c + 1 < NC);
    if (more) {
      const int nb = (c + 1) * CH;
      s0 = load_pad(td, nb + (tid          ) * 4, N);
      s1 = load_pad(td, nb + (tid +     BLK) * 4, N);
      s2 = load_pad(td, nb + (tid + 2 * BLK) * 4, N);
      s3 = load_pad(td, nb + (tid + 3 * BLK) * 4, N);
    }

    // compute current chunk from buf[c&1]
    const float4* l4 = (const float4*)lds[c & 1];
    #pragma unroll 4
    for (int k = 0; k < CH / 64; k += 2) {
      float4 v0 = l4[part + 16 * k];        // 4 distinct addrs/wave, 16-way
      float4 v1 = l4[part + 16 * k + 16];   //   broadcast, banks 0-15: clean
      v2f va = {v0.x, v0.y}, vb = {v0.z, v0.w};
      v2f vc = {v1.x, v1.y}, vd = {v1.z, v1.w};
      GROUP(va, n0, d0)
      GROUP(vb, n1, d1)
      GROUP(vc, n2, d2)
      GROUP(vd, n3, d3)
    }

    if (more) {
      // write next chunk into the idle buffer; prev iteration's barrier
      // guarantees every wave is done reading it. ONE barrier per chunk.
      float4* dst = (float4*)lds[(c + 1) & 1];
      dst[tid]           = s0;
      dst[tid +     BLK] = s1;
      dst[tid + 2 * BLK] = s2;
      dst[tid + 3 * BLK] = s3;
      __syncthreads();
    }
  }
#undef GROUP

  v2f numv = (n0 + n1) + (n2 + n3);
  v2f denv = (d0 + d1) + (d2 + d3);
  __syncthreads();   // all waves past last compute before reduce buffers fill
  nbuf[part * JB + jl] = numv.x + numv.y;
  dbuf[part * JB + jl] = denv.x + denv.y;
  __syncthreads();

  // Final combine: 16 threads, each sums 16 part-partials for its j.
  if (tid < JB && (blockIdx.x * JB + tid) < B) {
    const int jj = blockIdx.x * JB + tid;
    float num = 0.f, den = 0.f;
    #pragma unroll
    for (int p = 0; p < PARTS; ++p) {
      num += nbuf[p * JB + tid];   // lanes read consecutive floats: clean
      den += dbuf[p * JB + tid];
    }
    float sigma2 = sigma2_of(t[jj]);
    float evals = (den == 0.0f) ? 0.0f : (num / den);   // reference's guard
    out[jj] = (evals - x[jj]) / sigma2;
  }
}

extern "C" void kernel_launch(void* const* d_in, const int* in_sizes, int n_in,
                              void* d_out, int out_size, void* d_ws, size_t ws_size,
                              hipStream_t stream) {
  const float* x  = (const float*)d_in[0];
  const float* t  = (const float*)d_in[1];
  const float* td = (const float*)d_in[2];
  float* out = (float*)d_out;
  (void)d_ws; (void)ws_size;

  const int B = in_sizes[0];
  const int N = in_sizes[2];

  const int GX = (B + JB - 1) / JB;   // 1024 blocks for B=16384
  gmm_fused<<<GX, BLK, 0, stream>>>(x, t, td, out, N, B);
}